// Round 5
// baseline (750.301 us; speedup 1.0000x reference)
//
#include <hip/hip_runtime.h>
#include <hip/hip_bf16.h>
#include <cstdint>
#include <cstddef>

#define T_SEQ   2048
#define HIDDEN  5120
#define NH      32
#define DQ      128
#define DR      64
#define DV      128
#define Q_LORA  1536
#define KV_LORA 512
#define QD      (DQ + DR)          // 192
#define KVD     (KV_LORA + DR)     // 576
#define QROW    (NH * QD)          // 6144
#define KVUPROW (NH * (DQ + DV))   // 8192
#define AOROW   (NH * DV)          // 4096
#define FUSED_N (Q_LORA + KVD)     // 2112  (qa | kv_c | k_pe)
#define FUSED_PE (Q_LORA + KV_LORA)// 2048  (k_pe col offset in fused buf)

typedef short bf16x8 __attribute__((ext_vector_type(8)));   // 8 bf16 raw (4 VGPRs)
typedef float f32x4  __attribute__((ext_vector_type(4)));

// async global->LDS, 16B per lane (dest must be wave-linear: base + lane*16)
#define GLOAD16(gp, lp)                                                        \
    __builtin_amdgcn_global_load_lds(                                          \
        (const __attribute__((address_space(1))) void*)(gp),                   \
        (__attribute__((address_space(3))) void*)(lp), 16, 0, 0)

// fp32 -> bf16 raw bits, round-to-nearest-even
static __device__ __forceinline__ short f2bf(float f)
{
    union { float f; unsigned u; } v; v.f = f;
    unsigned r = v.u + 0x7FFFu + ((v.u >> 16) & 1u);
    return (short)(r >> 16);
}
static __device__ __forceinline__ float bf2f(short s)
{
    union { unsigned u; float f; } v;
    v.u = ((unsigned)(unsigned short)s) << 16;
    return v.f;
}

// tile-coord swizzle: XCD chunking + GROUP_M=4 grouped rasterization.
// Each XCD gets a contiguous chunk; within it, walk 4 bm-tiles fast then bn.
// Keeps the live A-slice (4x128 rows) L2-resident and cuts B re-fetch by 4x.
static __device__ __forceinline__ void tile_swizzle(int& bm, int& bn)
{
    const int gx  = gridDim.x;
    const int gy  = gridDim.y;
    const int nwg = gx * gy;
    int flat = blockIdx.y * gx + blockIdx.x;
    if ((nwg & 7) == 0) {
        const int chunk = nwg >> 3;
        flat = (flat & 7) * chunk + (flat >> 3);
    }
    if ((gy & 3) == 0) {
        const int g = flat / (4 * gx);
        const int r = flat - g * (4 * gx);
        bm = (g * 4 + (r & 3)) * 128;
        bn = (r >> 2) * 128;
    } else {
        bm = (flat / gx) * 128;
        bn = (flat % gx) * 128;
    }
}

// ---------------------------------------------------------------------------
// Grid-stride fp32 zero (for split-K atomic accumulation bases)
// ---------------------------------------------------------------------------
__global__ __launch_bounds__(256) void zero_f32(float* __restrict__ p, int n4)
{
    const int stride = gridDim.x * 256;
    for (int i = blockIdx.x * 256 + threadIdx.x; i < n4; i += stride)
        ((float4*)p)[i] = make_float4(0.f, 0.f, 0.f, 0.f);
}

// ---------------------------------------------------------------------------
// Elementwise fp32 -> bf16 (n % 2048 == 0)
// ---------------------------------------------------------------------------
__global__ __launch_bounds__(256) void conv_bf(
    const float* __restrict__ src, short* __restrict__ dst)
{
    const size_t i = ((size_t)blockIdx.x * 256 + threadIdx.x) * 8;
    float4 a = *(const float4*)&src[i];
    float4 b = *(const float4*)&src[i + 4];
    union { short s[8]; uint4 u; } o;
    o.s[0] = f2bf(a.x); o.s[1] = f2bf(a.y); o.s[2] = f2bf(a.z); o.s[3] = f2bf(a.w);
    o.s[4] = f2bf(b.x); o.s[5] = f2bf(b.y); o.s[6] = f2bf(b.z); o.s[7] = f2bf(b.w);
    *(uint4*)&dst[i] = o.u;
}

// ---------------------------------------------------------------------------
// Transpose + convert: src[K][N] f32 -> dst[N][K] bf16. 32x32 tiles, 256 thr.
// ---------------------------------------------------------------------------
__global__ __launch_bounds__(256) void tr_f32_bf16(
    const float* __restrict__ src, short* __restrict__ dst, int K, int N)
{
    const int k0 = blockIdx.x * 32, n0 = blockIdx.y * 32;
    __shared__ float t[32][33];
    const int tid = threadIdx.x;
    {
        const int r = tid >> 3, c4 = (tid & 7) * 4;
        float4 v = *(const float4*)&src[(size_t)(k0 + r) * N + n0 + c4];
        t[r][c4 + 0] = v.x; t[r][c4 + 1] = v.y;
        t[r][c4 + 2] = v.z; t[r][c4 + 3] = v.w;
    }
    __syncthreads();
    {
        const int n = tid >> 3, k4 = (tid & 7) * 4;
        union { short s[4]; uint2 u; } o;
#pragma unroll
        for (int j = 0; j < 4; ++j) o.s[j] = f2bf(t[k4 + j][n]);
        *(uint2*)&dst[(size_t)(n0 + n) * K + k0 + k4] = o.u;
    }
}

// ---------------------------------------------------------------------------
// bf16 MFMA GEMM, B pre-transposed: C[M,N] = A[M,K](bf16) @ BT[N,K](bf16)^T.
// m97 structure: 128x128 tile, BK=64, 4 waves 2x2, global_load_lds width=16,
// linear LDS, 2 barriers/step. Grouped+XCD tile swizzle; split-K via
// gridDim.z (fp32 output path uses atomicAdd; base pre-zeroed).
// N guard: clamp BT source row to N-1 (cols >= N masked at C-write).
// ---------------------------------------------------------------------------
__global__ __launch_bounds__(256, 4) void gemm_bt(
    const short* __restrict__ A, const short* __restrict__ BT,
    float* __restrict__ Cf, short* __restrict__ Cb, int N, int K,
    int lda, int ldbt, int ldc)
{
    __shared__ short As[128 * 64];
    __shared__ short Bs[128 * 64];

    int bm, bn;
    tile_swizzle(bm, bn);

    const int kchunk = K / gridDim.z;
    const int kbeg   = kchunk * blockIdx.z;
    const int kend   = kbeg + kchunk;

    const int tid  = threadIdx.x;
    const int w    = tid >> 6;
    const int l    = tid & 63;
    const int wm   = (w >> 1) * 64;
    const int wn   = (w & 1) * 64;
    const int quad = l >> 4;
    const int lrow = l & 15;

    f32x4 acc[4][4];
#pragma unroll
    for (int mt = 0; mt < 4; ++mt)
#pragma unroll
        for (int nt = 0; nt < 4; ++nt)
            acc[mt][nt] = (f32x4){0.f, 0.f, 0.f, 0.f};

    const int r0  = tid >> 3;          // id = tid + 256*i  ->  r = r0 + 32*i
    const int c8  = (tid & 7) * 8;
    const int rbA = bm + r0;
    int rbB = bn + r0; if (rbB > N - 1) rbB = N - 1;   // clamp (cols>=N masked)

    for (int k0 = kbeg; k0 < kend; k0 += 64) {
        __syncthreads();                       // prev iter's frag reads done
#pragma unroll
        for (int i = 0; i < 4; ++i) {
            const int r = r0 + 32 * i;
            GLOAD16(&A[(size_t)(rbA + 32 * i) * lda + k0 + c8], &As[r * 64 + c8]);
        }
#pragma unroll
        for (int i = 0; i < 4; ++i) {
            const int r  = r0 + 32 * i;
            int rb = rbB + 32 * i; if (rb > N - 1) rb = N - 1;
            GLOAD16(&BT[(size_t)rb * ldbt + k0 + c8], &Bs[r * 64 + c8]);
        }
        __syncthreads();                       // vmcnt(0) drain: LDS ready

#pragma unroll
        for (int ks = 0; ks < 2; ++ks) {
            bf16x8 af[4], bfr[4];
#pragma unroll
            for (int mt = 0; mt < 4; ++mt)
                af[mt] = *(const bf16x8*)&As[(wm + mt * 16 + lrow) * 64 + ks * 32 + quad * 8];
#pragma unroll
            for (int nt = 0; nt < 4; ++nt)
                bfr[nt] = *(const bf16x8*)&Bs[(wn + nt * 16 + lrow) * 64 + ks * 32 + quad * 8];
#pragma unroll
            for (int mt = 0; mt < 4; ++mt)
#pragma unroll
                for (int nt = 0; nt < 4; ++nt)
                    acc[mt][nt] = __builtin_amdgcn_mfma_f32_16x16x32_bf16(
                        af[mt], bfr[nt], acc[mt][nt], 0, 0, 0);
        }
    }

    // C/D layout: col = lane&15, row = quad*4 + i
    if (Cb == nullptr) {
        const bool atom = (gridDim.z > 1);
#pragma unroll
        for (int mt = 0; mt < 4; ++mt)
#pragma unroll
            for (int i = 0; i < 4; ++i) {
                const int row = bm + wm + mt * 16 + quad * 4 + i;
                float* crow = Cf + (size_t)row * ldc;
#pragma unroll
                for (int nt = 0; nt < 4; ++nt) {
                    const int col = bn + wn + nt * 16 + lrow;
                    if (col < N) {
                        if (atom) atomicAdd(&crow[col], acc[mt][nt][i]);
                        else      crow[col] = acc[mt][nt][i];
                    }
                }
            }
    } else {
#pragma unroll
        for (int mt = 0; mt < 4; ++mt)
#pragma unroll
            for (int i = 0; i < 4; ++i) {
                const int row = bm + wm + mt * 16 + quad * 4 + i;
                short* crow = Cb + (size_t)row * ldc;
#pragma unroll
                for (int nt = 0; nt < 4; ++nt) {
                    const int col = bn + wn + nt * 16 + lrow;
                    if (col < N) crow[col] = f2bf(acc[mt][nt][i]);
                }
            }
    }
}

// ---------------------------------------------------------------------------
// kv-up GEMM (same m97 structure + swizzle), epilogue into attn layouts:
//   cols h*256+d, d<128  -> Kg[h][row][d]   (bf16)
//   cols h*256+128+dv    -> Vg[h][dv][row]  (bf16, transposed)
// ---------------------------------------------------------------------------
__global__ __launch_bounds__(256, 4) void gemm_kv(
    const short* __restrict__ A, const short* __restrict__ BT,
    short* __restrict__ Kg, short* __restrict__ Vg)
{
    __shared__ short As[128 * 64];
    __shared__ short Bs[128 * 64];

    int bm, bn;
    tile_swizzle(bm, bn);

    const int tid  = threadIdx.x;
    const int w    = tid >> 6;
    const int l    = tid & 63;
    const int wm   = (w >> 1) * 64;
    const int wn   = (w & 1) * 64;
    const int quad = l >> 4;
    const int lrow = l & 15;

    f32x4 acc[4][4];
#pragma unroll
    for (int mt = 0; mt < 4; ++mt)
#pragma unroll
        for (int nt = 0; nt < 4; ++nt)
            acc[mt][nt] = (f32x4){0.f, 0.f, 0.f, 0.f};

    const int r0 = tid >> 3;
    const int c8 = (tid & 7) * 8;

    for (int k0 = 0; k0 < KV_LORA; k0 += 64) {
        __syncthreads();
#pragma unroll
        for (int i = 0; i < 4; ++i) {
            const int r = r0 + 32 * i;
            GLOAD16(&A[(size_t)(bm + r) * KV_LORA + k0 + c8], &As[r * 64 + c8]);
        }
#pragma unroll
        for (int i = 0; i < 4; ++i) {
            const int r = r0 + 32 * i;
            GLOAD16(&BT[(size_t)(bn + r) * KV_LORA + k0 + c8], &Bs[r * 64 + c8]);
        }
        __syncthreads();

#pragma unroll
        for (int ks = 0; ks < 2; ++ks) {
            bf16x8 af[4], bfr[4];
#pragma unroll
            for (int mt = 0; mt < 4; ++mt)
                af[mt] = *(const bf16x8*)&As[(wm + mt * 16 + lrow) * 64 + ks * 32 + quad * 8];
#pragma unroll
            for (int nt = 0; nt < 4; ++nt)
                bfr[nt] = *(const bf16x8*)&Bs[(wn + nt * 16 + lrow) * 64 + ks * 32 + quad * 8];
#pragma unroll
            for (int mt = 0; mt < 4; ++mt)
#pragma unroll
                for (int nt = 0; nt < 4; ++nt)
                    acc[mt][nt] = __builtin_amdgcn_mfma_f32_16x16x32_bf16(
                        af[mt], bfr[nt], acc[mt][nt], 0, 0, 0);
        }
    }

    const int  h     = bn >> 8;
    const bool vhalf = (bn & 128) != 0;
    if (!vhalf) {
        short* KgH = Kg + (size_t)h * (2048 * 192);
#pragma unroll
        for (int mt = 0; mt < 4; ++mt)
#pragma unroll
            for (int i = 0; i < 4; ++i) {
                const int row = bm + wm + mt * 16 + quad * 4 + i;
#pragma unroll
                for (int nt = 0; nt < 4; ++nt) {
                    const int d = wn + nt * 16 + lrow;
                    KgH[(size_t)row * 192 + d] = f2bf(acc[mt][nt][i]);
                }
            }
    } else {
        short* VgH = Vg + (size_t)h * (128 * 2048);
#pragma unroll
        for (int mt = 0; mt < 4; ++mt)
#pragma unroll
            for (int nt = 0; nt < 4; ++nt) {
                const int dv   = wn + nt * 16 + lrow;
                const int rowb = bm + wm + mt * 16 + quad * 4;
                union { short s[4]; uint2 u; } t;
                t.s[0] = f2bf(acc[mt][nt][0]); t.s[1] = f2bf(acc[mt][nt][1]);
                t.s[2] = f2bf(acc[mt][nt][2]); t.s[3] = f2bf(acc[mt][nt][3]);
                *(uint2*)&VgH[(size_t)dv * 2048 + rowb] = t.u;
            }
    }
}

// ---------------------------------------------------------------------------
// RMSNorm: fp32 in (in_stride) -> bf16 out (out_stride), first `len` cols.
// ---------------------------------------------------------------------------
__global__ __launch_bounds__(256) void rmsnorm_bf(
    const float* __restrict__ x, const float* __restrict__ g,
    short* __restrict__ y, int len, int in_stride, int out_stride)
{
    const float* xr = x + (size_t)blockIdx.x * in_stride;
    short*       yr = y + (size_t)blockIdx.x * out_stride;
    float ss = 0.f;
    for (int i = threadIdx.x; i < len; i += 256) {
        float v = xr[i];
        ss += v * v;
    }
#pragma unroll
    for (int off = 32; off > 0; off >>= 1) ss += __shfl_down(ss, off);
    __shared__ float red[4];
    if ((threadIdx.x & 63) == 0) red[threadIdx.x >> 6] = ss;
    __syncthreads();
    float tot = red[0] + red[1] + red[2] + red[3];
    float scale = rsqrtf(tot / (float)len + 1e-6f);
    for (int i = threadIdx.x; i < len; i += 256)
        yr[i] = f2bf(xr[i] * scale * g[i]);
}

// ---------------------------------------------------------------------------
// RoPE (GPT-J interleaved rotate, NEOX concatenated cos/sin)
// ---------------------------------------------------------------------------
#define ROPE_LN_THETA_OVER_32 0.28782313662425575f  // ln(10000)/32

__device__ __forceinline__ void rope_pair(float p, int i, float& x0, float& x1)
{
    const int   j0 = (2 * i) & 31;
    const int   j1 = (2 * i + 1) & 31;
    const float a0 = p * expf(-(float)j0 * ROPE_LN_THETA_OVER_32);
    const float a1 = p * expf(-(float)j1 * ROPE_LN_THETA_OVER_32);
    const float r0 = x0 * cosf(a0) - x1 * sinf(a0);
    const float r1 = x1 * cosf(a1) + x0 * sinf(a1);
    x0 = r0; x1 = r1;
}

// q_pe RoPE in place on bf16 qbuf
__global__ __launch_bounds__(256) void rope_q_bf(
    short* __restrict__ qb, const int* __restrict__ pos)
{
    const int idx = blockIdx.x * 256 + threadIdx.x;  // t*1024 + h*32 + i
    const int i = idx & 31;
    const int h = (idx >> 5) & 31;
    const int t = idx >> 10;
    short* base = qb + (size_t)t * QROW + h * QD + DQ;
    float x0 = bf2f(base[2 * i]), x1 = bf2f(base[2 * i + 1]);
    rope_pair((float)pos[t], i, x0, x1);
    union { short s[2]; unsigned u; } o;
    o.s[0] = f2bf(x0); o.s[1] = f2bf(x1);
    *(unsigned*)&base[2 * i] = o.u;
}

// k_pe RoPE: read fused-buf f32 pe cols, rotate, broadcast to all heads' Kg
__global__ __launch_bounds__(256) void rope_k_bcast(
    const float* __restrict__ qkva, const int* __restrict__ pos,
    short* __restrict__ Kg)
{
    const int idx = blockIdx.x * 256 + threadIdx.x;  // t*32 + i
    const int i = idx & 31;
    const int t = idx >> 5;
    const float* base = qkva + (size_t)t * FUSED_N + FUSED_PE;
    float x0 = base[2 * i], x1 = base[2 * i + 1];
    rope_pair((float)pos[t], i, x0, x1);
    union { short s[2]; unsigned u; } pk;
    pk.s[0] = f2bf(x0); pk.s[1] = f2bf(x1);
    for (int h = 0; h < NH; ++h)
        *(unsigned*)&Kg[((size_t)h * 2048 + t) * 192 + 128 + 2 * i] = pk.u;
}

// ---------------------------------------------------------------------------
// MFMA flash attention. bf16 Q in, bf16 out.
// K/V staged via global_load_lds into linear LDS with both-sides XOR swizzle.
// Q direct global->reg, exp2-domain softmax. This round: XCD-grouped head
// swizzle (4 heads per XCD chunk -> K/V L2 locality) + heavy-first order.
// Grid must be (NH=32, 32).
// ---------------------------------------------------------------------------
__global__ __launch_bounds__(256) void attn_mfma(
    const short* __restrict__ qb, const short* __restrict__ Kg,
    const short* __restrict__ Vg, short* __restrict__ aout)
{
    const int flat = blockIdx.y * 32 + blockIdx.x;     // 1024 blocks
    const int swz  = (flat & 7) * 128 + (flat >> 3);   // bijective XCD chunking
    const int h    = swz >> 5;                         // 4 heads per XCD chunk
    const int qb_  = 31 - (swz & 31);                  // heavy blocks first
    const int q0   = qb_ * 64;

    __shared__ short Ks[64 * 192];   // linear, swizzled contents
    __shared__ short Vt[128 * 64];   // linear, swizzled contents
    __shared__ short Ps[64 * 72];

    const int tid  = threadIdx.x;
    const int w    = tid >> 6;
    const int l    = tid & 63;
    const int quad = l >> 4;
    const int lrow = l & 15;

    // (1/sqrt(192)) * log2(e): softmax in exp2 domain, raw-score max tracking
    const float K2 = 0.104117547f;

    // Q fragments: direct global -> registers (once per block)
    bf16x8 afq[6];
    {
        const short* qrow = qb + (size_t)(q0 + w * 16 + lrow) * QROW + h * QD;
#pragma unroll
        for (int ks = 0; ks < 6; ++ks)
            afq[ks] = *(const bf16x8*)&qrow[ks * 32 + quad * 8];
    }

    f32x4 Oacc[8];
#pragma unroll
    for (int nt = 0; nt < 8; ++nt) Oacc[nt] = (f32x4){0.f, 0.f, 0.f, 0.f};
    float m_run[4] = {-1e30f, -1e30f, -1e30f, -1e30f};
    float l_run[4] = {0.f, 0.f, 0.f, 0.f};

    const short* KgH = Kg + (size_t)h * (2048 * 192);
    const short* VgH = Vg + (size_t)h * (128 * 2048);

    for (int kt = 0; kt <= qb_; ++kt) {
        __syncthreads();                 // prev tile's LDS reads done
        // K tile 64x192: linear dest Ks[id*8]; source col XOR'd by row
#pragma unroll
        for (int it = 0; it < 6; ++it) {
            const int id = tid + 256 * it;
            const int r = id / 24, g = id % 24;
            const int sc = (g * 8) ^ ((r & 7) << 3);      // swizzled src col
            GLOAD16(&KgH[(size_t)(kt * 64 + r) * 192 + sc], &Ks[id * 8]);
        }
        // V tile 128x64: linear dest Vt[id*8]; source col XOR'd by row
#pragma unroll
        for (int it = 0; it < 4; ++it) {
            const int id = tid + 256 * it;
            const int rv = id >> 3, g = id & 7;
            const int sc = (g * 8) ^ ((rv & 7) << 3);
            GLOAD16(&VgH[(size_t)rv * 2048 + kt * 64 + sc], &Vt[id * 8]);
        }
        __syncthreads();                 // vmcnt(0) drain: LDS ready

        f32x4 Sc[4];
#pragma unroll
        for (int nt = 0; nt < 4; ++nt) Sc[nt] = (f32x4){0.f, 0.f, 0.f, 0.f};
#pragma unroll
        for (int ks = 0; ks < 6; ++ks)
#pragma unroll
            for (int nt = 0; nt < 4; ++nt) {
                const int row = nt * 16 + lrow;
                const int col = (ks * 32 + quad * 8) ^ ((row & 7) << 3);
                bf16x8 bk = *(const bf16x8*)&Ks[row * 192 + col];
                Sc[nt] = __builtin_amdgcn_mfma_f32_16x16x32_bf16(afq[ks], bk, Sc[nt], 0, 0, 0);
            }

        if (kt == qb_) {   // diagonal tile: causal mask (raw domain)
            const int qrow = w * 16 + quad * 4;
#pragma unroll
            for (int nt = 0; nt < 4; ++nt)
#pragma unroll
                for (int i = 0; i < 4; ++i)
                    if (nt * 16 + lrow > qrow + i) Sc[nt][i] = -1e30f;
        }

        float alpha[4], negmk[4];
#pragma unroll
        for (int i = 0; i < 4; ++i) {
            float m = fmaxf(fmaxf(Sc[0][i], Sc[1][i]), fmaxf(Sc[2][i], Sc[3][i]));
            m = fmaxf(m, __shfl_xor(m, 1));
            m = fmaxf(m, __shfl_xor(m, 2));
            m = fmaxf(m, __shfl_xor(m, 4));
            m = fmaxf(m, __shfl_xor(m, 8));
            const float mn = fmaxf(m_run[i], m);
            negmk[i] = -mn * K2;
            alpha[i] = exp2f(fmaf(m_run[i], K2, negmk[i]));
            m_run[i] = mn;
        }

        float rs[4] = {0.f, 0.f, 0.f, 0.f};
#pragma unroll
        for (int nt = 0; nt < 4; ++nt)
#pragma unroll
            for (int i = 0; i < 4; ++i) {
                const float p = exp2f(fmaf(Sc[nt][i], K2, negmk[i]));
                rs[i] += p;
                Ps[(w * 16 + quad * 4 + i) * 72 + nt * 16 + lrow] = f2bf(p);
            }
#pragma unroll
        for (int i = 0; i < 4; ++i) {
            float r = rs[i];
            r += __shfl_xor(r, 1);
            r += __shfl_xor(r, 2);
            r += __shfl_xor(r, 4);
            r += __shfl_xor(r, 8);
            l_run[i] = l_run[i] * alpha[i] + r;
        }

#pragma unroll
        for (int nt = 0; nt < 8; ++nt)
#pragma unroll
            for (int i = 0; i < 4; ++i) Oacc[nt][i] *= alpha[i];

#pragma unroll
        for (int ks2 = 0; ks2 < 2; ++ks2) {
            bf16x8 ap = *(const bf16x8*)&Ps[(w * 16 + lrow) * 72 + ks2 * 32 + quad * 8];
#pragma unroll
            for (int nt = 0; nt < 8; ++nt) {
                const int row = nt * 16 + lrow;
                const int col = (ks2 * 32 + quad * 8) ^ ((row & 7) << 3);
                bf16x8 bv = *(const bf16x8*)&Vt[row * 64 + col];
                Oacc[nt] = __builtin_amdgcn_mfma_f32_16x16x32_bf16(ap, bv, Oacc[nt], 0, 0, 0);
            }
        }
    }

    float invl[4];
#pragma unroll
    for (int i = 0; i < 4; ++i) invl[i] = 1.f / l_run[i];
#pragma unroll
    for (int nt = 0; nt < 8; ++nt)
#pragma unroll
        for (int i = 0; i < 4; ++i)
            aout[(size_t)(q0 + w * 16 + quad * 4 + i) * AOROW + h * 128 + nt * 16 + lrow]
                = f2bf(Oacc[nt][i] * invl[i]);
}

// ---------------------------------------------------------------------------
extern "C" void kernel_launch(void* const* d_in, const int* in_sizes, int n_in,
                              void* d_out, int out_size, void* d_ws, size_t ws_size,
                              hipStream_t stream)
{
    const int*   positions = (const int*)d_in[0];
    const float* hidden    = (const float*)d_in[1];
    const float* w_qa      = (const float*)d_in[2];
    const float* gamma_q   = (const float*)d_in[3];
    const float* w_qb      = (const float*)d_in[4];
    const float* w_kva     = (const float*)d_in[5];
    const float* gamma_kv  = (const float*)d_in[6];
    const float* w_kvb     = (const float*)d_in[7];
    const float* w_o       = (const float*)d_in[8];
    float*       out       = (float*)d_out;

    // Workspace layout (~155 MB). wT reused for each weight's B^T.
    short* wT      = (short*)d_ws;                 // max 5120*4096 = 20,971,520 shorts
    short* hid_bf  = wT      + (size_t)20971520;   // [2048][5120]
    short* qbuf_bf = hid_bf  + (size_t)T_SEQ * HIDDEN;   // [2048][6144]
    short* Kg      = qbuf_bf + (size_t)T_SEQ * QROW;     // [32][2048][192]
    short* Vg      = Kg      + (size_t)NH * 2048 * 192;  // [32][128][2048]
    short* aout_bf = Vg      + (size_t)NH * 128 * 2048;  // [2048][4096]
    short* qa_bf   = aout_bf + (size_t)T_SEQ * AOROW;    // [2048][1536]
    short* kvc_bf  = qa_bf   + (size_t)T_SEQ * Q_LORA;   // [2048][512]
    // fused qa|kv_c|k_pe fp32 buffer [2048][2112] aliases Vg (dead before
    // gemm_kv writes Vg).
    float* qkva    = (float*)Vg;

    const dim3 blk(256);

    // 0) zero split-K accumulation bases; hidden -> bf16
    zero_f32<<<dim3(2048), blk, 0, stream>>>(qkva, T_SEQ * FUSED_N / 4);
    zero_f32<<<dim3(2048), blk, 0, stream>>>(out, T_SEQ * HIDDEN / 4);
    conv_bf<<<dim3(T_SEQ * HIDDEN / 8 / 256), blk, 0, stream>>>(hidden, hid_bf);

    // 1) fused qa|kva: wT = [w_qa^T ; w_kva^T]
    tr_f32_bf16<<<dim3(HIDDEN / 32, Q_LORA / 32), blk, 0, stream>>>(w_qa, wT, HIDDEN, Q_LORA);
    tr_f32_bf16<<<dim3(HIDDEN / 32, KVD / 32), blk, 0, stream>>>(
        w_kva, wT + (size_t)Q_LORA * HIDDEN, HIDDEN, KVD);
    gemm_bt<<<dim3((FUSED_N + 127) / 128, T_SEQ / 128, 2), blk, 0, stream>>>(
        hid_bf, wT, qkva, nullptr, FUSED_N, HIDDEN, HIDDEN, HIDDEN, FUSED_N);

    // 2) rmsnorms on fused buffer slices
    rmsnorm_bf<<<dim3(T_SEQ), blk, 0, stream>>>(qkva, gamma_q, qa_bf, Q_LORA, FUSED_N, Q_LORA);
    rmsnorm_bf<<<dim3(T_SEQ), blk, 0, stream>>>(qkva + Q_LORA, gamma_kv, kvc_bf,
                                                KV_LORA, FUSED_N, KV_LORA);
    // 3) RoPE k_pe -> broadcast into Kg pe cols (reads qkva; precedes gemm_kv)
    rope_k_bcast<<<dim3(T_SEQ * 32 / 256), blk, 0, stream>>>(qkva, positions, Kg);

    // 4) qbuf = qa_bf @ w_qb  (bf16 out)
    tr_f32_bf16<<<dim3(Q_LORA / 32, QROW / 32), blk, 0, stream>>>(w_qb, wT, Q_LORA, QROW);
    gemm_bt<<<dim3(QROW / 128, T_SEQ / 128, 1), blk, 0, stream>>>(
        qa_bf, wT, nullptr, qbuf_bf, QROW, Q_LORA, Q_LORA, Q_LORA, QROW);

    // 5) kv-up -> Kg nope + Vg transposed (qkva dead from here)
    tr_f32_bf16<<<dim3(KV_LORA / 32, KVUPROW / 32), blk, 0, stream>>>(w_kvb, wT, KV_LORA, KVUPROW);
    gemm_kv<<<dim3(KVUPROW / 128, T_SEQ / 128), blk, 0, stream>>>(kvc_bf, wT, Kg, Vg);

    // 6) RoPE q_pe in place (bf16 qbuf)
    rope_q_bf<<<dim3(T_SEQ * NH * 32 / 256), blk, 0, stream>>>(qbuf_bf, positions);

    // 7) MFMA flash attention -> aout bf16
    attn_mfma<<<dim3(NH, T_SEQ / 64), blk, 0, stream>>>(qbuf_bf, Kg, Vg, aout_bf);

    // 8) out = aout @ w_o (fp32, split-K x2, atomic into zeroed out)
    tr_f32_bf16<<<dim3(AOROW / 32, HIDDEN / 32), blk, 0, stream>>>(w_o, wT, AOROW, HIDDEN);
    gemm_bt<<<dim3(HIDDEN / 128, T_SEQ / 128, 2), blk, 0, stream>>>(
        aout_bf, wT, out, nullptr, HIDDEN, AOROW, AOROW, AOROW, HIDDEN);
}

// Round 6
// 701.078 us; speedup vs baseline: 1.0702x; 1.0702x over previous
//
#include <hip/hip_runtime.h>
#include <hip/hip_bf16.h>
#include <cstdint>
#include <cstddef>

#define T_SEQ   2048
#define HIDDEN  5120
#define NH      32
#define DQ      128
#define DR      64
#define DV      128
#define Q_LORA  1536
#define KV_LORA 512
#define QD      (DQ + DR)          // 192
#define KVD     (KV_LORA + DR)     // 576
#define QROW    (NH * QD)          // 6144
#define KVUPROW (NH * (DQ + DV))   // 8192
#define AOROW   (NH * DV)          // 4096
#define FUSED_N (Q_LORA + KVD)     // 2112  (qa | kv_c | k_pe)
#define FUSED_PE (Q_LORA + KV_LORA)// 2048  (k_pe col offset in fused buf)

typedef short bf16x8 __attribute__((ext_vector_type(8)));   // 8 bf16 raw (4 VGPRs)
typedef float f32x4  __attribute__((ext_vector_type(4)));

// async global->LDS, 16B per lane (dest must be wave-linear: base + lane*16)
#define GLOAD16(gp, lp)                                                        \
    __builtin_amdgcn_global_load_lds(                                          \
        (const __attribute__((address_space(1))) void*)(gp),                   \
        (__attribute__((address_space(3))) void*)(lp), 16, 0, 0)

// fp32 -> bf16 raw bits, round-to-nearest-even
static __device__ __forceinline__ short f2bf(float f)
{
    union { float f; unsigned u; } v; v.f = f;
    unsigned r = v.u + 0x7FFFu + ((v.u >> 16) & 1u);
    return (short)(r >> 16);
}
static __device__ __forceinline__ float bf2f(short s)
{
    union { unsigned u; float f; } v;
    v.u = ((unsigned)(unsigned short)s) << 16;
    return v.f;
}

// tile-coord swizzle: XCD chunking + GROUP_M=4 grouped rasterization.
static __device__ __forceinline__ void tile_swizzle(int& bm, int& bn)
{
    const int gx  = gridDim.x;
    const int gy  = gridDim.y;
    const int nwg = gx * gy;
    int flat = blockIdx.y * gx + blockIdx.x;
    if ((nwg & 7) == 0) {
        const int chunk = nwg >> 3;
        flat = (flat & 7) * chunk + (flat >> 3);
    }
    if ((gy & 3) == 0) {
        const int g = flat / (4 * gx);
        const int r = flat - g * (4 * gx);
        bm = (g * 4 + (r & 3)) * 128;
        bn = (r >> 2) * 128;
    } else {
        bm = (flat / gx) * 128;
        bn = (flat % gx) * 128;
    }
}

// ---------------------------------------------------------------------------
// Grid-stride fp32 zero (for split-K atomic accumulation bases)
// ---------------------------------------------------------------------------
__global__ __launch_bounds__(256) void zero_f32(float* __restrict__ p, int n4)
{
    const int stride = gridDim.x * 256;
    for (int i = blockIdx.x * 256 + threadIdx.x; i < n4; i += stride)
        ((float4*)p)[i] = make_float4(0.f, 0.f, 0.f, 0.f);
}

// ---------------------------------------------------------------------------
// Elementwise fp32 -> bf16 (n % 2048 == 0)
// ---------------------------------------------------------------------------
__global__ __launch_bounds__(256) void conv_bf(
    const float* __restrict__ src, short* __restrict__ dst)
{
    const size_t i = ((size_t)blockIdx.x * 256 + threadIdx.x) * 8;
    float4 a = *(const float4*)&src[i];
    float4 b = *(const float4*)&src[i + 4];
    union { short s[8]; uint4 u; } o;
    o.s[0] = f2bf(a.x); o.s[1] = f2bf(a.y); o.s[2] = f2bf(a.z); o.s[3] = f2bf(a.w);
    o.s[4] = f2bf(b.x); o.s[5] = f2bf(b.y); o.s[6] = f2bf(b.z); o.s[7] = f2bf(b.w);
    *(uint4*)&dst[i] = o.u;
}

// ---------------------------------------------------------------------------
// Transpose + convert: src[K][N] f32 -> dst[N][K] bf16. 32x32 tiles, 256 thr.
// ---------------------------------------------------------------------------
__global__ __launch_bounds__(256) void tr_f32_bf16(
    const float* __restrict__ src, short* __restrict__ dst, int K, int N)
{
    const int k0 = blockIdx.x * 32, n0 = blockIdx.y * 32;
    __shared__ float t[32][33];
    const int tid = threadIdx.x;
    {
        const int r = tid >> 3, c4 = (tid & 7) * 4;
        float4 v = *(const float4*)&src[(size_t)(k0 + r) * N + n0 + c4];
        t[r][c4 + 0] = v.x; t[r][c4 + 1] = v.y;
        t[r][c4 + 2] = v.z; t[r][c4 + 3] = v.w;
    }
    __syncthreads();
    {
        const int n = tid >> 3, k4 = (tid & 7) * 4;
        union { short s[4]; uint2 u; } o;
#pragma unroll
        for (int j = 0; j < 4; ++j) o.s[j] = f2bf(t[k4 + j][n]);
        *(uint2*)&dst[(size_t)(n0 + n) * K + k0 + k4] = o.u;
    }
}

// ---------------------------------------------------------------------------
// bf16 MFMA GEMM, B pre-transposed: C[M,N] = A[M,K](bf16) @ BT[N,K](bf16)^T.
// m97 structure: 128x128 tile, BK=64, 4 waves 2x2, global_load_lds width=16,
// linear LDS, 2 barriers/step. Grouped+XCD tile swizzle; split-K via
// gridDim.z (fp32 output path uses atomicAdd; base pre-zeroed).
// ---------------------------------------------------------------------------
__global__ __launch_bounds__(256, 4) void gemm_bt(
    const short* __restrict__ A, const short* __restrict__ BT,
    float* __restrict__ Cf, short* __restrict__ Cb, int N, int K,
    int lda, int ldbt, int ldc)
{
    __shared__ short As[128 * 64];
    __shared__ short Bs[128 * 64];

    int bm, bn;
    tile_swizzle(bm, bn);

    const int kchunk = K / gridDim.z;
    const int kbeg   = kchunk * blockIdx.z;
    const int kend   = kbeg + kchunk;

    const int tid  = threadIdx.x;
    const int w    = tid >> 6;
    const int l    = tid & 63;
    const int wm   = (w >> 1) * 64;
    const int wn   = (w & 1) * 64;
    const int quad = l >> 4;
    const int lrow = l & 15;

    f32x4 acc[4][4];
#pragma unroll
    for (int mt = 0; mt < 4; ++mt)
#pragma unroll
        for (int nt = 0; nt < 4; ++nt)
            acc[mt][nt] = (f32x4){0.f, 0.f, 0.f, 0.f};

    const int r0  = tid >> 3;          // id = tid + 256*i  ->  r = r0 + 32*i
    const int c8  = (tid & 7) * 8;
    const int rbA = bm + r0;
    int rbB = bn + r0; if (rbB > N - 1) rbB = N - 1;   // clamp (cols>=N masked)

    for (int k0 = kbeg; k0 < kend; k0 += 64) {
        __syncthreads();                       // prev iter's frag reads done
#pragma unroll
        for (int i = 0; i < 4; ++i) {
            const int r = r0 + 32 * i;
            GLOAD16(&A[(size_t)(rbA + 32 * i) * lda + k0 + c8], &As[r * 64 + c8]);
        }
#pragma unroll
        for (int i = 0; i < 4; ++i) {
            const int r  = r0 + 32 * i;
            int rb = rbB + 32 * i; if (rb > N - 1) rb = N - 1;
            GLOAD16(&BT[(size_t)rb * ldbt + k0 + c8], &Bs[r * 64 + c8]);
        }
        __syncthreads();                       // vmcnt(0) drain: LDS ready

#pragma unroll
        for (int ks = 0; ks < 2; ++ks) {
            bf16x8 af[4], bfr[4];
#pragma unroll
            for (int mt = 0; mt < 4; ++mt)
                af[mt] = *(const bf16x8*)&As[(wm + mt * 16 + lrow) * 64 + ks * 32 + quad * 8];
#pragma unroll
            for (int nt = 0; nt < 4; ++nt)
                bfr[nt] = *(const bf16x8*)&Bs[(wn + nt * 16 + lrow) * 64 + ks * 32 + quad * 8];
#pragma unroll
            for (int mt = 0; mt < 4; ++mt)
#pragma unroll
                for (int nt = 0; nt < 4; ++nt)
                    acc[mt][nt] = __builtin_amdgcn_mfma_f32_16x16x32_bf16(
                        af[mt], bfr[nt], acc[mt][nt], 0, 0, 0);
        }
    }

    // C/D layout: col = lane&15, row = quad*4 + i
    if (Cb == nullptr) {
        const bool atom = (gridDim.z > 1);
#pragma unroll
        for (int mt = 0; mt < 4; ++mt)
#pragma unroll
            for (int i = 0; i < 4; ++i) {
                const int row = bm + wm + mt * 16 + quad * 4 + i;
                float* crow = Cf + (size_t)row * ldc;
#pragma unroll
                for (int nt = 0; nt < 4; ++nt) {
                    const int col = bn + wn + nt * 16 + lrow;
                    if (col < N) {
                        if (atom) atomicAdd(&crow[col], acc[mt][nt][i]);
                        else      crow[col] = acc[mt][nt][i];
                    }
                }
            }
    } else {
#pragma unroll
        for (int mt = 0; mt < 4; ++mt)
#pragma unroll
            for (int i = 0; i < 4; ++i) {
                const int row = bm + wm + mt * 16 + quad * 4 + i;
                short* crow = Cb + (size_t)row * ldc;
#pragma unroll
                for (int nt = 0; nt < 4; ++nt) {
                    const int col = bn + wn + nt * 16 + lrow;
                    if (col < N) crow[col] = f2bf(acc[mt][nt][i]);
                }
            }
    }
}

// ---------------------------------------------------------------------------
// kv-up GEMM (same m97 structure + swizzle), epilogue into attn layouts:
//   cols h*256+d, d<128  -> Kg[h][row][d]   (bf16)
//   cols h*256+128+dv    -> Vg[h][dv][row]  (bf16, transposed)
// ---------------------------------------------------------------------------
__global__ __launch_bounds__(256, 4) void gemm_kv(
    const short* __restrict__ A, const short* __restrict__ BT,
    short* __restrict__ Kg, short* __restrict__ Vg)
{
    __shared__ short As[128 * 64];
    __shared__ short Bs[128 * 64];

    int bm, bn;
    tile_swizzle(bm, bn);

    const int tid  = threadIdx.x;
    const int w    = tid >> 6;
    const int l    = tid & 63;
    const int wm   = (w >> 1) * 64;
    const int wn   = (w & 1) * 64;
    const int quad = l >> 4;
    const int lrow = l & 15;

    f32x4 acc[4][4];
#pragma unroll
    for (int mt = 0; mt < 4; ++mt)
#pragma unroll
        for (int nt = 0; nt < 4; ++nt)
            acc[mt][nt] = (f32x4){0.f, 0.f, 0.f, 0.f};

    const int r0 = tid >> 3;
    const int c8 = (tid & 7) * 8;

    for (int k0 = 0; k0 < KV_LORA; k0 += 64) {
        __syncthreads();
#pragma unroll
        for (int i = 0; i < 4; ++i) {
            const int r = r0 + 32 * i;
            GLOAD16(&A[(size_t)(bm + r) * KV_LORA + k0 + c8], &As[r * 64 + c8]);
        }
#pragma unroll
        for (int i = 0; i < 4; ++i) {
            const int r = r0 + 32 * i;
            GLOAD16(&BT[(size_t)(bn + r) * KV_LORA + k0 + c8], &Bs[r * 64 + c8]);
        }
        __syncthreads();

#pragma unroll
        for (int ks = 0; ks < 2; ++ks) {
            bf16x8 af[4], bfr[4];
#pragma unroll
            for (int mt = 0; mt < 4; ++mt)
                af[mt] = *(const bf16x8*)&As[(wm + mt * 16 + lrow) * 64 + ks * 32 + quad * 8];
#pragma unroll
            for (int nt = 0; nt < 4; ++nt)
                bfr[nt] = *(const bf16x8*)&Bs[(wn + nt * 16 + lrow) * 64 + ks * 32 + quad * 8];
#pragma unroll
            for (int mt = 0; mt < 4; ++mt)
#pragma unroll
                for (int nt = 0; nt < 4; ++nt)
                    acc[mt][nt] = __builtin_amdgcn_mfma_f32_16x16x32_bf16(
                        af[mt], bfr[nt], acc[mt][nt], 0, 0, 0);
        }
    }

    const int  h     = bn >> 8;
    const bool vhalf = (bn & 128) != 0;
    if (!vhalf) {
        short* KgH = Kg + (size_t)h * (2048 * 192);
#pragma unroll
        for (int mt = 0; mt < 4; ++mt)
#pragma unroll
            for (int i = 0; i < 4; ++i) {
                const int row = bm + wm + mt * 16 + quad * 4 + i;
#pragma unroll
                for (int nt = 0; nt < 4; ++nt) {
                    const int d = wn + nt * 16 + lrow;
                    KgH[(size_t)row * 192 + d] = f2bf(acc[mt][nt][i]);
                }
            }
    } else {
        short* VgH = Vg + (size_t)h * (128 * 2048);
#pragma unroll
        for (int mt = 0; mt < 4; ++mt)
#pragma unroll
            for (int nt = 0; nt < 4; ++nt) {
                const int dv   = wn + nt * 16 + lrow;
                const int rowb = bm + wm + mt * 16 + quad * 4;
                union { short s[4]; uint2 u; } t;
                t.s[0] = f2bf(acc[mt][nt][0]); t.s[1] = f2bf(acc[mt][nt][1]);
                t.s[2] = f2bf(acc[mt][nt][2]); t.s[3] = f2bf(acc[mt][nt][3]);
                *(uint2*)&VgH[(size_t)dv * 2048 + rowb] = t.u;
            }
    }
}

// ---------------------------------------------------------------------------
// RMSNorm: fp32 in (in_stride) -> bf16 out (out_stride), first `len` cols.
// ---------------------------------------------------------------------------
__global__ __launch_bounds__(256) void rmsnorm_bf(
    const float* __restrict__ x, const float* __restrict__ g,
    short* __restrict__ y, int len, int in_stride, int out_stride)
{
    const float* xr = x + (size_t)blockIdx.x * in_stride;
    short*       yr = y + (size_t)blockIdx.x * out_stride;
    float ss = 0.f;
    for (int i = threadIdx.x; i < len; i += 256) {
        float v = xr[i];
        ss += v * v;
    }
#pragma unroll
    for (int off = 32; off > 0; off >>= 1) ss += __shfl_down(ss, off);
    __shared__ float red[4];
    if ((threadIdx.x & 63) == 0) red[threadIdx.x >> 6] = ss;
    __syncthreads();
    float tot = red[0] + red[1] + red[2] + red[3];
    float scale = rsqrtf(tot / (float)len + 1e-6f);
    for (int i = threadIdx.x; i < len; i += 256)
        yr[i] = f2bf(xr[i] * scale * g[i]);
}

// ---------------------------------------------------------------------------
// RoPE (GPT-J interleaved rotate, NEOX concatenated cos/sin)
// ---------------------------------------------------------------------------
#define ROPE_LN_THETA_OVER_32 0.28782313662425575f  // ln(10000)/32

__device__ __forceinline__ void rope_pair(float p, int i, float& x0, float& x1)
{
    const int   j0 = (2 * i) & 31;
    const int   j1 = (2 * i + 1) & 31;
    const float a0 = p * expf(-(float)j0 * ROPE_LN_THETA_OVER_32);
    const float a1 = p * expf(-(float)j1 * ROPE_LN_THETA_OVER_32);
    const float r0 = x0 * cosf(a0) - x1 * sinf(a0);
    const float r1 = x1 * cosf(a1) + x0 * sinf(a1);
    x0 = r0; x1 = r1;
}

// q_pe RoPE in place on bf16 qbuf
__global__ __launch_bounds__(256) void rope_q_bf(
    short* __restrict__ qb, const int* __restrict__ pos)
{
    const int idx = blockIdx.x * 256 + threadIdx.x;  // t*1024 + h*32 + i
    const int i = idx & 31;
    const int h = (idx >> 5) & 31;
    const int t = idx >> 10;
    short* base = qb + (size_t)t * QROW + h * QD + DQ;
    float x0 = bf2f(base[2 * i]), x1 = bf2f(base[2 * i + 1]);
    rope_pair((float)pos[t], i, x0, x1);
    union { short s[2]; unsigned u; } o;
    o.s[0] = f2bf(x0); o.s[1] = f2bf(x1);
    *(unsigned*)&base[2 * i] = o.u;
}

// k_pe RoPE: read fused-buf f32 pe cols, rotate, broadcast to all heads' Kg
__global__ __launch_bounds__(256) void rope_k_bcast(
    const float* __restrict__ qkva, const int* __restrict__ pos,
    short* __restrict__ Kg)
{
    const int idx = blockIdx.x * 256 + threadIdx.x;  // t*32 + i
    const int i = idx & 31;
    const int t = idx >> 5;
    const float* base = qkva + (size_t)t * FUSED_N + FUSED_PE;
    float x0 = base[2 * i], x1 = base[2 * i + 1];
    rope_pair((float)pos[t], i, x0, x1);
    union { short s[2]; unsigned u; } pk;
    pk.s[0] = f2bf(x0); pk.s[1] = f2bf(x1);
    for (int h = 0; h < NH; ++h)
        *(unsigned*)&Kg[((size_t)h * 2048 + t) * 192 + 128 + 2 * i] = pk.u;
}

// ---------------------------------------------------------------------------
// MFMA flash attention, QBLK=128 (512 threads, 8 waves). bf16 Q in, bf16 out.
// K/V staged via global_load_lds into linear LDS with both-sides XOR swizzle;
// one staged K/V tile feeds 2x the MFMA work vs QBLK=64 (staging+barrier
// amortization). Q direct global->reg, exp2-domain softmax, heavy-first.
// Grid: (NH, T_SEQ/128).
// ---------------------------------------------------------------------------
__global__ __launch_bounds__(512) void attn_mfma(
    const short* __restrict__ qb, const short* __restrict__ Kg,
    const short* __restrict__ Vg, short* __restrict__ aout)
{
    const int h   = blockIdx.x;                   // h%8 = XCD (32%8==0)
    const int qb_ = gridDim.y - 1 - blockIdx.y;   // heavy blocks dispatch first
    const int q0  = qb_ * 128;

    __shared__ short Ks[64 * 192];   // linear, swizzled contents (24 KB)
    __shared__ short Vt[128 * 64];   // linear, swizzled contents (16 KB)
    __shared__ short Ps[128 * 72];   // P round-trip (18 KB)

    const int tid  = threadIdx.x;
    const int w    = tid >> 6;       // 0..7
    const int l    = tid & 63;
    const int quad = l >> 4;
    const int lrow = l & 15;

    // (1/sqrt(192)) * log2(e): softmax in exp2 domain, raw-score max tracking
    const float K2 = 0.104117547f;

    // Q fragments: direct global -> registers (once per block)
    bf16x8 afq[6];
    {
        const short* qrow = qb + (size_t)(q0 + w * 16 + lrow) * QROW + h * QD;
#pragma unroll
        for (int ks = 0; ks < 6; ++ks)
            afq[ks] = *(const bf16x8*)&qrow[ks * 32 + quad * 8];
    }

    f32x4 Oacc[8];
#pragma unroll
    for (int nt = 0; nt < 8; ++nt) Oacc[nt] = (f32x4){0.f, 0.f, 0.f, 0.f};
    float m_run[4] = {-1e30f, -1e30f, -1e30f, -1e30f};
    float l_run[4] = {0.f, 0.f, 0.f, 0.f};

    const short* KgH = Kg + (size_t)h * (2048 * 192);
    const short* VgH = Vg + (size_t)h * (128 * 2048);

    const int ktmax = 2 * qb_ + 1;
    for (int kt = 0; kt <= ktmax; ++kt) {
        __syncthreads();                 // prev tile's LDS reads done
        // K tile 64x192: linear dest Ks[id*8]; source col XOR'd by row
#pragma unroll
        for (int it = 0; it < 3; ++it) {
            const int id = tid + 512 * it;          // 0..1535
            const int r = id / 24, g = id % 24;
            const int sc = (g * 8) ^ ((r & 7) << 3);
            GLOAD16(&KgH[(size_t)(kt * 64 + r) * 192 + sc], &Ks[id * 8]);
        }
        // V tile 128x64: linear dest Vt[id*8]; source col XOR'd by row
#pragma unroll
        for (int it = 0; it < 2; ++it) {
            const int id = tid + 512 * it;          // 0..1023
            const int rv = id >> 3, g = id & 7;
            const int sc = (g * 8) ^ ((rv & 7) << 3);
            GLOAD16(&VgH[(size_t)rv * 2048 + kt * 64 + sc], &Vt[id * 8]);
        }
        __syncthreads();                 // vmcnt(0) drain: LDS ready

        f32x4 Sc[4];
#pragma unroll
        for (int nt = 0; nt < 4; ++nt) Sc[nt] = (f32x4){0.f, 0.f, 0.f, 0.f};
#pragma unroll
        for (int ks = 0; ks < 6; ++ks)
#pragma unroll
            for (int nt = 0; nt < 4; ++nt) {
                const int row = nt * 16 + lrow;
                const int col = (ks * 32 + quad * 8) ^ ((row & 7) << 3);
                bf16x8 bk = *(const bf16x8*)&Ks[row * 192 + col];
                Sc[nt] = __builtin_amdgcn_mfma_f32_16x16x32_bf16(afq[ks], bk, Sc[nt], 0, 0, 0);
            }

        if (kt >= 2 * qb_) {   // diagonal tiles: causal mask (raw domain)
            const int koff = (kt - 2 * qb_) * 64;   // 0 or 64
            const int qrow = w * 16 + quad * 4;
#pragma unroll
            for (int nt = 0; nt < 4; ++nt)
#pragma unroll
                for (int i = 0; i < 4; ++i)
                    if (nt * 16 + lrow + koff > qrow + i) Sc[nt][i] = -1e30f;
        }

        float alpha[4], negmk[4];
#pragma unroll
        for (int i = 0; i < 4; ++i) {
            float m = fmaxf(fmaxf(Sc[0][i], Sc[1][i]), fmaxf(Sc[2][i], Sc[3][i]));
            m = fmaxf(m, __shfl_xor(m, 1));
            m = fmaxf(m, __shfl_xor(m, 2));
            m = fmaxf(m, __shfl_xor(m, 4));
            m = fmaxf(m, __shfl_xor(m, 8));
            const float mn = fmaxf(m_run[i], m);
            negmk[i] = -mn * K2;
            alpha[i] = exp2f(fmaf(m_run[i], K2, negmk[i]));
            m_run[i] = mn;
        }

        float rs[4] = {0.f, 0.f, 0.f, 0.f};
#pragma unroll
        for (int nt = 0; nt < 4; ++nt)
#pragma unroll
            for (int i = 0; i < 4; ++i) {
                const float p = exp2f(fmaf(Sc[nt][i], K2, negmk[i]));
                rs[i] += p;
                Ps[(w * 16 + quad * 4 + i) * 72 + nt * 16 + lrow] = f2bf(p);
            }
#pragma unroll
        for (int i = 0; i < 4; ++i) {
            float r = rs[i];
            r += __shfl_xor(r, 1);
            r += __shfl_xor(r, 2);
            r += __shfl_xor(r, 4);
            r += __shfl_xor(r, 8);
            l_run[i] = l_run[i] * alpha[i] + r;
        }

#pragma unroll
        for (int nt = 0; nt < 8; ++nt)
#pragma unroll
            for (int i = 0; i < 4; ++i) Oacc[nt][i] *= alpha[i];

#pragma unroll
        for (int ks2 = 0; ks2 < 2; ++ks2) {
            bf16x8 ap = *(const bf16x8*)&Ps[(w * 16 + lrow) * 72 + ks2 * 32 + quad * 8];
#pragma unroll
            for (int nt = 0; nt < 8; ++nt) {
                const int row = nt * 16 + lrow;
                const int col = (ks2 * 32 + quad * 8) ^ ((row & 7) << 3);
                bf16x8 bv = *(const bf16x8*)&Vt[row * 64 + col];
                Oacc[nt] = __builtin_amdgcn_mfma_f32_16x16x32_bf16(ap, bv, Oacc[nt], 0, 0, 0);
            }
        }
    }

    float invl[4];
#pragma unroll
    for (int i = 0; i < 4; ++i) invl[i] = 1.f / l_run[i];
#pragma unroll
    for (int nt = 0; nt < 8; ++nt)
#pragma unroll
        for (int i = 0; i < 4; ++i)
            aout[(size_t)(q0 + w * 16 + quad * 4 + i) * AOROW + h * 128 + nt * 16 + lrow]
                = f2bf(Oacc[nt][i] * invl[i]);
}

// ---------------------------------------------------------------------------
extern "C" void kernel_launch(void* const* d_in, const int* in_sizes, int n_in,
                              void* d_out, int out_size, void* d_ws, size_t ws_size,
                              hipStream_t stream)
{
    const int*   positions = (const int*)d_in[0];
    const float* hidden    = (const float*)d_in[1];
    const float* w_qa      = (const float*)d_in[2];
    const float* gamma_q   = (const float*)d_in[3];
    const float* w_qb      = (const float*)d_in[4];
    const float* w_kva     = (const float*)d_in[5];
    const float* gamma_kv  = (const float*)d_in[6];
    const float* w_kvb     = (const float*)d_in[7];
    const float* w_o       = (const float*)d_in[8];
    float*       out       = (float*)d_out;

    // Workspace layout (~155 MB). wT reused for each weight's B^T.
    short* wT      = (short*)d_ws;                 // max 5120*4096 = 20,971,520 shorts
    short* hid_bf  = wT      + (size_t)20971520;   // [2048][5120]
    short* qbuf_bf = hid_bf  + (size_t)T_SEQ * HIDDEN;   // [2048][6144]
    short* Kg      = qbuf_bf + (size_t)T_SEQ * QROW;     // [32][2048][192]
    short* Vg      = Kg      + (size_t)NH * 2048 * 192;  // [32][128][2048]
    short* aout_bf = Vg      + (size_t)NH * 128 * 2048;  // [2048][4096]
    short* qa_bf   = aout_bf + (size_t)T_SEQ * AOROW;    // [2048][1536]
    short* kvc_bf  = qa_bf   + (size_t)T_SEQ * Q_LORA;   // [2048][512]
    // fused qa|kv_c|k_pe fp32 buffer [2048][2112] aliases Vg (dead before
    // gemm_kv writes Vg).
    float* qkva    = (float*)Vg;

    const dim3 blk(256);

    // 0) zero split-K accumulation bases; hidden -> bf16
    zero_f32<<<dim3(2048), blk, 0, stream>>>(qkva, T_SEQ * FUSED_N / 4);
    zero_f32<<<dim3(2048), blk, 0, stream>>>(out, T_SEQ * HIDDEN / 4);
    conv_bf<<<dim3(T_SEQ * HIDDEN / 8 / 256), blk, 0, stream>>>(hidden, hid_bf);

    // 1) fused qa|kva: wT = [w_qa^T ; w_kva^T]
    tr_f32_bf16<<<dim3(HIDDEN / 32, Q_LORA / 32), blk, 0, stream>>>(w_qa, wT, HIDDEN, Q_LORA);
    tr_f32_bf16<<<dim3(HIDDEN / 32, KVD / 32), blk, 0, stream>>>(
        w_kva, wT + (size_t)Q_LORA * HIDDEN, HIDDEN, KVD);
    gemm_bt<<<dim3((FUSED_N + 127) / 128, T_SEQ / 128, 2), blk, 0, stream>>>(
        hid_bf, wT, qkva, nullptr, FUSED_N, HIDDEN, HIDDEN, HIDDEN, FUSED_N);

    // 2) rmsnorms on fused buffer slices
    rmsnorm_bf<<<dim3(T_SEQ), blk, 0, stream>>>(qkva, gamma_q, qa_bf, Q_LORA, FUSED_N, Q_LORA);
    rmsnorm_bf<<<dim3(T_SEQ), blk, 0, stream>>>(qkva + Q_LORA, gamma_kv, kvc_bf,
                                                KV_LORA, FUSED_N, KV_LORA);
    // 3) RoPE k_pe -> broadcast into Kg pe cols (reads qkva; precedes gemm_kv)
    rope_k_bcast<<<dim3(T_SEQ * 32 / 256), blk, 0, stream>>>(qkva, positions, Kg);

    // 4) qbuf = qa_bf @ w_qb  (bf16 out)
    tr_f32_bf16<<<dim3(Q_LORA / 32, QROW / 32), blk, 0, stream>>>(w_qb, wT, Q_LORA, QROW);
    gemm_bt<<<dim3(QROW / 128, T_SEQ / 128, 1), blk, 0, stream>>>(
        qa_bf, wT, nullptr, qbuf_bf, QROW, Q_LORA, Q_LORA, Q_LORA, QROW);

    // 5) kv-up -> Kg nope + Vg transposed (qkva dead from here)
    tr_f32_bf16<<<dim3(KV_LORA / 32, KVUPROW / 32), blk, 0, stream>>>(w_kvb, wT, KV_LORA, KVUPROW);
    gemm_kv<<<dim3(KVUPROW / 128, T_SEQ / 128), blk, 0, stream>>>(kvc_bf, wT, Kg, Vg);

    // 6) RoPE q_pe in place (bf16 qbuf)
    rope_q_bf<<<dim3(T_SEQ * NH * 32 / 256), blk, 0, stream>>>(qbuf_bf, positions);

    // 7) MFMA flash attention -> aout bf16 (512-thread blocks, QBLK=128)
    attn_mfma<<<dim3(NH, T_SEQ / 128), dim3(512), 0, stream>>>(qbuf_bf, Kg, Vg, aout_bf);

    // 8) out = aout @ w_o (fp32, split-K x2, atomic into zeroed out)
    tr_f32_bf16<<<dim3(AOROW / 32, HIDDEN / 32), blk, 0, stream>>>(w_o, wT, AOROW, HIDDEN);
    gemm_bt<<<dim3(HIDDEN / 128, T_SEQ / 128, 2), blk, 0, stream>>>(
        aout_bf, wT, out, nullptr, HIDDEN, AOROW, AOROW, AOROW, HIDDEN);
}